// Round 7
// baseline (675.765 us; speedup 1.0000x reference)
//
#include <hip/hip_runtime.h>

#define E_EDGES   1000000
#define NNODES    2048
#define HCH       128
#define KP        136            // w1t / A row stride in bf16: 128 z + 4 attr + bias + 3 pad
#define TILE      64
#define NTILES    (E_EDGES / TILE)   // 15625 exact
#define NSPREAD   8
#define GRID_GEMM 2048
#define ZVEC      (32 * 2048 * 64 / 4)   // 1048576 float4s
#define ZBLK      2048
#define WBLK      66             // 66*256 = 132*128 w1t transpose elements
#define HBLK      128            // histogram blocks
#define NBIN      8              // edge bins by src>>13 (1 MB zb working set each)
#define NRUN      3907           // ceil(1e6 / 256) scatter wave-runs
#define SBLK      977            // ceil(3907 / 4)

typedef short  shortx8 __attribute__((ext_vector_type(8)));
typedef float  floatx4 __attribute__((ext_vector_type(4)));

__device__ __forceinline__ unsigned short f2bf(float f) {
  union { float f; unsigned int u; } v; v.f = f;
  unsigned int r = (v.u + 0x7fffu + ((v.u >> 16) & 1u)) >> 16;
  return (unsigned short)r;
}
__device__ __forceinline__ void cfence() { asm volatile("" ::: "memory"); }
// lgkm-only barrier: LDS writes visible, vmem prefetches stay in flight.
__device__ __forceinline__ void bar_lds() {
  asm volatile("s_waitcnt lgkmcnt(0)" ::: "memory");
  __builtin_amdgcn_s_barrier();
  cfence();
}
__device__ __forceinline__ unsigned pack_rows(int s, int d) {
  unsigned rs = (unsigned)s & 0xFFFFu;
  unsigned rd = (unsigned)(((s & ~(NNODES - 1)) | (d & (NNODES - 1)))) & 0xFFFFu;
  return rs | (rd << 16);
}

// ---------------------------------------------------------------- prep ----
__global__ void k_prep(const float* __restrict__ z, const float* __restrict__ W1,
                       const float* __restrict__ b1, const int* __restrict__ ei,
                       unsigned short* __restrict__ zb, unsigned short* __restrict__ w1t,
                       float* __restrict__ gstats, int* __restrict__ hist) {
  int bid = blockIdx.x;
  if (bid < ZBLK) {
    const float4* z4 = (const float4*)z;
    ushort4* zb4 = (ushort4*)zb;
    for (int i = bid * 256 + threadIdx.x; i < ZVEC; i += ZBLK * 256) {
      float4 v = z4[i];
      ushort4 o;
      o.x = f2bf(v.x); o.y = f2bf(v.y); o.z = f2bf(v.z); o.w = f2bf(v.w);
      zb4[i] = o;
    }
  } else if (bid < ZBLK + WBLK) {
    int idx = (bid - ZBLK) * 256 + threadIdx.x;   // 0..16895 = 132*128
    int k = idx >> 7, n = idx & 127;              // coalesced read of W1
    w1t[n * KP + k] = f2bf(W1[idx]);
  } else if (bid == ZBLK + WBLK) {
    int tid = threadIdx.x;
    if (tid < 512) {   // pad k=132..135: bias at 132, zeros after
      int n = tid >> 2, kp = 132 + (tid & 3);
      w1t[n * KP + kp] = (kp == 132) ? f2bf(b1[n]) : (unsigned short)0;
    }
    for (int i = tid; i < NSPREAD * 2 * HCH; i += 256) gstats[i] = 0.f;
  } else {
    // histogram of src>>13 into 8 bins (LDS-staged)
    __shared__ int lh[NBIN];
    int tid = threadIdx.x;
    if (tid < NBIN) lh[tid] = 0;
    __syncthreads();
    int hb = bid - (ZBLK + WBLK + 1);
    for (int e = hb * 256 + tid; e < E_EDGES; e += HBLK * 256)
      atomicAdd(&lh[((unsigned)ei[e]) >> 13], 1);
    __syncthreads();
    if (tid < NBIN) atomicAdd(&hist[tid], lh[tid]);
  }
}

// ------------------------------------------------------------- scatter ----
// Bucket edges by bin = src>>13 into 16-B records:
//   {packed_rows, attr01 bf16x2, attr23 bf16x2, orig_index}
// Each wave owns a 256-edge run; one atomicAdd per (wave, bin).
__global__ __launch_bounds__(256)
void k_scatter(const int* __restrict__ ei, const float* __restrict__ attr,
               const int* __restrict__ hist, int* __restrict__ cur,
               uint4* __restrict__ recs) {
  __shared__ int spfx[NBIN];
  if (threadIdx.x == 0) {
    int a = 0;
    for (int b = 0; b < NBIN; ++b) { spfx[b] = a; a += hist[b]; }
  }
  __syncthreads();
  const int wid  = blockIdx.x * 4 + (threadIdx.x >> 6);
  const int lane = threadIdx.x & 63;
  if (wid >= NRUN) return;
  const int e0 = wid * 256;

  int s[4], d[4], bin[4];
  float4 at[4];
  bool val[4];
#pragma unroll
  for (int k = 0; k < 4; ++k) {
    int e = e0 + k * 64 + lane;
    val[k] = (e < E_EDGES);
    if (val[k]) {
      s[k] = ei[e];
      d[k] = ei[E_EDGES + e];
      at[k] = ((const float4*)attr)[e];
      bin[k] = ((unsigned)s[k]) >> 13;
    } else bin[k] = -1;
  }

  int slot[4];
  const unsigned long long below = (lane == 63) ? ~0ull >> 1
                                 : ((1ull << (lane + 1)) - 1) >> 1;  // lanes < lane
#pragma unroll
  for (int bb = 0; bb < NBIN; ++bb) {
    unsigned long long m[4];
    int pre[4], tot = 0;
#pragma unroll
    for (int k = 0; k < 4; ++k) {
      m[k] = __ballot(bin[k] == bb);
      pre[k] = tot;
      tot += __popcll(m[k]);
    }
    int base = 0;
    if (tot) {
      if (lane == 0) base = atomicAdd(&cur[bb], tot);
      base = __shfl(base, 0);
#pragma unroll
      for (int k = 0; k < 4; ++k)
        if (bin[k] == bb)
          slot[k] = spfx[bb] + base + pre[k] + __popcll(m[k] & below);
    }
  }

#pragma unroll
  for (int k = 0; k < 4; ++k)
    if (val[k]) {
      uint4 r;
      r.x = pack_rows(s[k], d[k]);
      r.y = (unsigned)f2bf(at[k].x) | ((unsigned)f2bf(at[k].y) << 16);
      r.z = (unsigned)f2bf(at[k].z) | ((unsigned)f2bf(at[k].w) << 16);
      r.w = (unsigned)(e0 + k * 64 + lane);
      recs[slot[k]] = r;
    }
}

// ---------------------------------------------------------------- gemm ----
// R1 structure on bucketed records: reg-staged gather (now L2-hot: each tile's
// 128 row reads hit one ~1 MB bin region), double-buffered A, one lgkm-only
// barrier per tile, 1-tile reg prefetch. Wave (eh,nh): edges eh*32..+31,
// channels nh*64..+63.
template<bool OUT>
__global__ __launch_bounds__(256, 2)
void k_gemm(const unsigned short* __restrict__ zb,
            const unsigned short* __restrict__ w1t,
            const uint4* __restrict__ recs,
            float* __restrict__ gstats,
            const float* __restrict__ gamma,
            const float* __restrict__ beta,
            const float* __restrict__ W2,
            const float* __restrict__ b2,
            float* __restrict__ out) {
  __shared__ __align__(16) unsigned short A[2][TILE * KP];   // 34816 B
  __shared__ float s_sum[HCH], s_sq[HCH];
  __shared__ float po[2][TILE];

  const int tid  = threadIdx.x;
  const int lane = tid & 63;
  const int wave = tid >> 6;
  const int l15  = lane & 15;
  const int quad = lane >> 4;
  const int eh   = wave >> 1;
  const int nh   = wave & 1;
  const int e    = tid >> 2;     // this thread's edge within tile
  const int q    = tid & 3;      // quarter: 0,1 = src halves; 2,3 = dst halves
  const int grid = GRID_GEMM;

  // ---- B fragments in registers
  shortx8 bfr[4][4], bfr4[4];
#pragma unroll
  for (int nt = 0; nt < 4; ++nt) {
    const unsigned short* bp = w1t + (nh * 64 + nt * 16 + l15) * KP;
#pragma unroll
    for (int kk = 0; kk < 4; ++kk)
      bfr[nt][kk] = *(const shortx8*)(bp + kk * 32 + quad * 8);
    bfr4[nt] = (quad == 0) ? *(const shortx8*)(bp + 128)
                           : (shortx8){0, 0, 0, 0, 0, 0, 0, 0};
  }

  float ea[4], ebb[4], ew2[4], b2v = 0.f;
  float ssum[4] = {0.f, 0.f, 0.f, 0.f}, ssq[4] = {0.f, 0.f, 0.f, 0.f};
  if (OUT) {
#pragma unroll
    for (int nt = 0; nt < 4; ++nt) {
      int c = nh * 64 + nt * 16 + l15;
      float S = 0.f, Q = 0.f;
#pragma unroll
      for (int i = 0; i < NSPREAD; ++i) {
        S += gstats[i * 2 * HCH + c];
        Q += gstats[i * 2 * HCH + HCH + c];
      }
      float mu   = S * (1.0f / (float)E_EDGES);
      float var  = Q * (1.0f / (float)E_EDGES) - mu * mu;
      float rstd = rsqrtf(var + 1e-5f);
      float a = gamma[c] * rstd;
      ea[nt]  = a;
      ebb[nt] = beta[c] - mu * a;
      ew2[nt] = W2[c];
    }
    b2v = b2[0];
  } else {
    if (tid < HCH) { s_sum[tid] = 0.f; s_sq[tid] = 0.f; }
  }

  auto stage = [&](uint4 rec, const uint4* g, int buf) {
    uint4* dst = (uint4*)(&A[buf][0] + e * KP + q * 32);
    dst[0] = g[0]; dst[1] = g[1]; dst[2] = g[2]; dst[3] = g[3];
    if (q == 0) {
      ushort4 av; av.x = (unsigned short)rec.y; av.y = (unsigned short)(rec.y >> 16);
      av.z = (unsigned short)rec.z; av.w = (unsigned short)(rec.z >> 16);
      *(ushort4*)(&A[buf][0] + e * KP + 128) = av;
      ushort4 bl; bl.x = 0x3F80; bl.y = 0; bl.z = 0; bl.w = 0;
      *(ushort4*)(&A[buf][0] + e * KP + 132) = bl;
    }
  };
  auto gather = [&](uint4 rec, uint4* g) {
    unsigned row = (q < 2) ? (rec.x & 0xFFFFu) : (rec.x >> 16);
    const uint4* sp = (const uint4*)(zb + (size_t)row * 64 + (q & 1) * 32);
    g[0] = sp[0]; g[1] = sp[1]; g[2] = sp[2]; g[3] = sp[3];
  };

  // ---- prologue: stage t0, prefetch t1 into regs
  const int t0 = blockIdx.x;
  uint4 recN, g[4];
  {
    uint4 recA = recs[t0 * TILE + e];
    gather(recA, g);
    stage(recA, g, 0);
    recN = recs[(t0 + grid) * TILE + e];     // t0+grid < NTILES always (2048 << 15625)
    gather(recN, g);
  }
  bar_lds();

  int pp = 0, sl = 0;
  for (int tile = t0; ; ) {
    const int tnext = tile + grid;
    const bool more = tnext < NTILES;

    uint4 recF;
    if (more) {
      stage(recN, g, pp ^ 1);                 // counted vmcnt wait on g (compiler)
      int tC = tile + 2 * grid; if (tC > NTILES - 1) tC = NTILES - 1;
      recF = recs[tC * TILE + e];             // issue early; value used after MFMA
    }

    // ---- MFMA on A[pp]
    const unsigned short* Ar = &A[pp][0];
    floatx4 acc[2][4];
#pragma unroll
    for (int mt = 0; mt < 2; ++mt)
#pragma unroll
      for (int nt = 0; nt < 4; ++nt)
        acc[mt][nt] = (floatx4){0.f, 0.f, 0.f, 0.f};

#pragma unroll
    for (int kk = 0; kk < 4; ++kk) {
      shortx8 afr[2];
#pragma unroll
      for (int mt = 0; mt < 2; ++mt)
        afr[mt] = *(const shortx8*)(Ar + (eh * 32 + mt * 16 + l15) * KP + kk * 32 + quad * 8);
#pragma unroll
      for (int mt = 0; mt < 2; ++mt)
#pragma unroll
        for (int nt = 0; nt < 4; ++nt)
          acc[mt][nt] = __builtin_amdgcn_mfma_f32_16x16x32_bf16(
              afr[mt], bfr[nt][kk], acc[mt][nt], 0, 0, 0);
    }
    {   // kk=4: attr+bias; A-side zero on quads 1-3 annihilates everything there
      shortx8 a4[2];
#pragma unroll
      for (int mt = 0; mt < 2; ++mt)
        a4[mt] = (quad == 0)
            ? *(const shortx8*)(Ar + (eh * 32 + mt * 16 + l15) * KP + 128)
            : (shortx8){0, 0, 0, 0, 0, 0, 0, 0};
#pragma unroll
      for (int mt = 0; mt < 2; ++mt)
#pragma unroll
        for (int nt = 0; nt < 4; ++nt)
          acc[mt][nt] = __builtin_amdgcn_mfma_f32_16x16x32_bf16(
              a4[mt], bfr4[nt], acc[mt][nt], 0, 0, 0);
    }

    if (more) gather(recF, g);                // t+2 gather; hidden under epilogue/next MFMA

    // ---- epilogue for 'tile'
    float tpart[2][4];
    if (!OUT) {
      // C/D layout: col = lane&15 (channel), row = quad*4 + reg (edge)
#pragma unroll
      for (int nt = 0; nt < 4; ++nt) {
        float s = 0.f, qq = 0.f;
#pragma unroll
        for (int mt = 0; mt < 2; ++mt)
#pragma unroll
          for (int r = 0; r < 4; ++r) {
            float h = acc[mt][nt][r];
            s += h; qq += h * h;
          }
        ssum[nt] += s; ssq[nt] += qq;
      }
    } else {
#pragma unroll
      for (int mt = 0; mt < 2; ++mt)
#pragma unroll
        for (int r = 0; r < 4; ++r) {
          float t = 0.f;
#pragma unroll
          for (int nt = 0; nt < 4; ++nt) {
            float h = acc[mt][nt][r];
            float p = ea[nt] * h + ebb[nt];
            p = (p >= 0.f) ? p : 0.2f * p;
            t += p * ew2[nt];
          }
          t += __shfl_xor(t, 1);
          t += __shfl_xor(t, 2);
          t += __shfl_xor(t, 4);
          t += __shfl_xor(t, 8);   // sum over this wave's 64 channels
          tpart[mt][r] = t;
        }
      if (nh == 1 && l15 == 0) {
#pragma unroll
        for (int mt = 0; mt < 2; ++mt)
#pragma unroll
          for (int r = 0; r < 4; ++r)
            po[sl][eh * 32 + mt * 16 + quad * 4 + r] = tpart[mt][r];
      }
    }

    bar_lds();   // staged A[pp^1] + po visible; g(t+2) loads stay in flight

    if (OUT && nh == 0 && l15 == 0) {
#pragma unroll
      for (int mt = 0; mt < 2; ++mt)
#pragma unroll
        for (int r = 0; r < 4; ++r) {
          int el = eh * 32 + mt * 16 + quad * 4 + r;
          int orig = ((const int*)recs)[(tile * TILE + el) * 4 + 3];
          out[orig] = tpart[mt][r] + po[sl][el] + b2v;
        }
    }

    if (!more) break;
    recN = recF;
    pp ^= 1; sl ^= 1;
    tile = tnext;
  }

  if (!OUT) {
#pragma unroll
    for (int nt = 0; nt < 4; ++nt) {
      float s = ssum[nt], qq = ssq[nt];
      s += __shfl_xor(s, 16); s += __shfl_xor(s, 32);
      qq += __shfl_xor(qq, 16); qq += __shfl_xor(qq, 32);
      if (quad == 0) {
        atomicAdd(&s_sum[nh * 64 + nt * 16 + l15], s);
        atomicAdd(&s_sq [nh * 64 + nt * 16 + l15], qq);
      }
    }
    __syncthreads();
    float* dstc = gstats + (blockIdx.x & (NSPREAD - 1)) * 2 * HCH;
    if (tid < HCH)          atomicAdd(&dstc[tid], s_sum[tid]);
    else if (tid < 2 * HCH) atomicAdd(&dstc[tid], s_sq[tid - HCH]);
  }
}

// -------------------------------------------------------------- launch ----
extern "C" void kernel_launch(void* const* d_in, const int* in_sizes, int n_in,
                              void* d_out, int out_size, void* d_ws, size_t ws_size,
                              hipStream_t stream) {
  const float* z     = (const float*)d_in[0];
  const float* attr  = (const float*)d_in[1];
  const float* W1    = (const float*)d_in[2];
  const float* b1    = (const float*)d_in[3];
  const float* gamma = (const float*)d_in[4];
  const float* beta  = (const float*)d_in[5];
  const float* W2    = (const float*)d_in[6];
  const float* b2    = (const float*)d_in[7];
  const int*   ei    = (const int*)d_in[8];
  float* out = (float*)d_out;

  char* ws = (char*)d_ws;
  unsigned short* zb  = (unsigned short*)ws;                 //  8,388,608 B
  unsigned short* w1t = (unsigned short*)(ws + 8388608);     //     34,816 B
  float* gstats       = (float*)(ws + 8423424);              //      8,192 B
  int* hist           = (int*)(ws + 8431616);                //         32 B
  int* cur            = (int*)(ws + 8431648);                //         32 B
  uint4* recs         = (uint4*)(ws + 8431680);              // 16,000,000 B

  hipMemsetAsync(ws + 8431616, 0, 64, stream);               // hist + cur
  k_prep<<<ZBLK + WBLK + 1 + HBLK, 256, 0, stream>>>(z, W1, b1, ei, zb, w1t,
                                                     gstats, hist);
  k_scatter<<<SBLK, 256, 0, stream>>>(ei, attr, hist, cur, recs);
  k_gemm<false><<<GRID_GEMM, 256, 0, stream>>>(zb, w1t, recs, gstats,
                                               gamma, beta, W2, b2, nullptr);
  k_gemm<true><<<GRID_GEMM, 256, 0, stream>>>(zb, w1t, recs, gstats,
                                              gamma, beta, W2, b2, out);
}

// Round 8
// 210.189 us; speedup vs baseline: 3.2150x; 3.2150x over previous
//
#include <hip/hip_runtime.h>

#define E_EDGES   1000000
#define NNODES    2048
#define HCH       128
#define KP        136            // A/w1t row stride bf16: 128 z + 4 attr + bias + 3 zero
#define TILE      64
#define NTILES    (E_EDGES / TILE)   // 15625 exact
#define NSPREAD   8
#define GRID_GEMM 1024           // 4 blocks/CU resident
#define ZVEC      (32 * 2048 * 64 / 4)
#define ZBLK      2048
#define WBLK      66             // 66*256 = 132*128 w1t transpose elements

typedef short  shortx8 __attribute__((ext_vector_type(8)));
typedef float  floatx4 __attribute__((ext_vector_type(4)));

__device__ __forceinline__ unsigned short f2bf(float f) {
  union { float f; unsigned int u; } v; v.f = f;
  unsigned int r = (v.u + 0x7fffu + ((v.u >> 16) & 1u)) >> 16;
  return (unsigned short)r;
}
__device__ __forceinline__ void cfence() { asm volatile("" ::: "memory"); }
// lgkm-only barrier: LDS writes visible; vmem prefetches stay in flight.
__device__ __forceinline__ void bar_lds() {
  asm volatile("s_waitcnt lgkmcnt(0)" ::: "memory");
  __builtin_amdgcn_s_barrier();
  cfence();
}

// ---------------------------------------------------------------- prep ----
__global__ void k_prep(const float* __restrict__ z, const float* __restrict__ W1,
                       const float* __restrict__ b1,
                       unsigned short* __restrict__ zb, unsigned short* __restrict__ w1t,
                       float* __restrict__ gstats) {
  int bid = blockIdx.x;
  if (bid < ZBLK) {
    const float4* z4 = (const float4*)z;
    ushort4* zb4 = (ushort4*)zb;
    for (int i = bid * 256 + threadIdx.x; i < ZVEC; i += ZBLK * 256) {
      float4 v = z4[i];
      ushort4 o;
      o.x = f2bf(v.x); o.y = f2bf(v.y); o.z = f2bf(v.z); o.w = f2bf(v.w);
      zb4[i] = o;
    }
  } else if (bid < ZBLK + WBLK) {
    int idx = (bid - ZBLK) * 256 + threadIdx.x;   // 0..16895 = 132*128
    int k = idx >> 7, n = idx & 127;              // coalesced read of W1
    w1t[n * KP + k] = f2bf(W1[idx]);
  } else {
    int tid = threadIdx.x;
    if (tid < 512) {   // pad k=132..135: bias at 132, zeros after
      int n = tid >> 2, kp = 132 + (tid & 3);
      w1t[n * KP + kp] = (kp == 132) ? f2bf(b1[n]) : (unsigned short)0;
    }
    for (int i = tid; i < NSPREAD * 2 * HCH; i += 256) gstats[i] = 0.f;
  }
}

// ---------------------------------------------------------------- gemm ----
// Occupancy-4 repartition: wave w owns channels w*32..+31 for ALL 64 edges.
// Per-wave regs: bfr 40 + acc 8 (m-tiles sequential, acc reused) -> fits
// __launch_bounds__(256,4) spill-free => 16 waves/CU (2x R1's TLP).
// Loop: reg-gather prefetch 1 tile ahead, double-buffered A, ONE lgkm-only
// barrier per tile (vmem prefetches cross it in flight).
template<bool OUT>
__global__ __launch_bounds__(256, 4)
void k_gemm(const unsigned short* __restrict__ zb,
            const unsigned short* __restrict__ w1t,
            const int* __restrict__ ei,
            const float* __restrict__ attr,
            float* __restrict__ gstats,
            const float* __restrict__ gamma,
            const float* __restrict__ beta,
            const float* __restrict__ W2,
            const float* __restrict__ b2,
            float* __restrict__ out) {
  __shared__ __align__(16) unsigned short A[2][TILE * KP];   // 34816 B
  __shared__ float po[2][4][TILE];                           //  2048 B

  const int tid  = threadIdx.x;
  const int lane = tid & 63;
  const int w    = tid >> 6;      // channel quarter
  const int l15  = lane & 15;
  const int quad = lane >> 4;
  const int e    = tid >> 2;      // this thread's edge within tile (staging)
  const int q    = tid & 3;       // quarter: 0,1 src halves; 2,3 dst halves

  // ---- B fragments: 2 n-tiles x 5 k-steps for this wave's 32 channels
  shortx8 bfr[2][4], bfr4[2];
#pragma unroll
  for (int nt = 0; nt < 2; ++nt) {
    const unsigned short* bp = w1t + (w * 32 + nt * 16 + l15) * KP;
#pragma unroll
    for (int kk = 0; kk < 4; ++kk)
      bfr[nt][kk] = *(const shortx8*)(bp + kk * 32 + quad * 8);
    bfr4[nt] = (quad == 0) ? *(const shortx8*)(bp + 128)
                           : (shortx8){0, 0, 0, 0, 0, 0, 0, 0};
  }

  float ea[2], ebb[2], ew2[2], b2v = 0.f;
  float ssum[2] = {0.f, 0.f}, ssq[2] = {0.f, 0.f};
  if (OUT) {
#pragma unroll
    for (int nt = 0; nt < 2; ++nt) {
      int c = w * 32 + nt * 16 + l15;
      float S = 0.f, Q = 0.f;
#pragma unroll
      for (int i = 0; i < NSPREAD; ++i) {
        S += gstats[i * 2 * HCH + c];
        Q += gstats[i * 2 * HCH + HCH + c];
      }
      float mu   = S * (1.0f / (float)E_EDGES);
      float var  = Q * (1.0f / (float)E_EDGES) - mu * mu;
      float rstd = rsqrtf(var + 1e-5f);
      float a = gamma[c] * rstd;
      ea[nt]  = a;
      ebb[nt] = beta[c] - mu * a;
      ew2[nt] = W2[c];
    }
    b2v = b2[0];
  }

  // ---- one-time: constant bias block (k=132..135) in both buffers
  if (tid < 128) {
    int b = tid >> 6, r = tid & 63;
    ushort4 bl; bl.x = 0x3F80; bl.y = 0; bl.z = 0; bl.w = 0;
    *(ushort4*)(&A[b][0] + r * KP + 132) = bl;
  }

  // ---- prologue: stage t0, prefetch gather(t1) + ei(t2)
  const int t0 = blockIdx.x;
  uint4 g0, g1, g2, g3;
  float4 av;
  int sF, dF;
  {
    int s = ei[t0 * TILE + e], d = ei[E_EDGES + t0 * TILE + e];
    if (w == 0) av = ((const float4*)attr)[t0 * TILE + tid];
    unsigned row = (q < 2) ? (unsigned)s
                           : (((unsigned)s & ~(unsigned)(NNODES - 1)) |
                              ((unsigned)d & (unsigned)(NNODES - 1)));
    const uint4* sp = (const uint4*)(zb + (size_t)row * 64 + (q & 1) * 32);
    g0 = sp[0]; g1 = sp[1]; g2 = sp[2]; g3 = sp[3];
    uint4* dst = (uint4*)(&A[0][0] + e * KP + q * 32);
    dst[0] = g0; dst[1] = g1; dst[2] = g2; dst[3] = g3;
    if (w == 0) {
      ushort4 a0; a0.x = f2bf(av.x); a0.y = f2bf(av.y);
      a0.z = f2bf(av.z); a0.w = f2bf(av.w);
      *(ushort4*)(&A[0][0] + tid * KP + 128) = a0;
    }
    // t1 (t0+GRID < NTILES always)
    int t1 = t0 + GRID_GEMM;
    s = ei[t1 * TILE + e]; d = ei[E_EDGES + t1 * TILE + e];
    if (w == 0) av = ((const float4*)attr)[t1 * TILE + tid];
    row = (q < 2) ? (unsigned)s
                  : (((unsigned)s & ~(unsigned)(NNODES - 1)) |
                     ((unsigned)d & (unsigned)(NNODES - 1)));
    sp = (const uint4*)(zb + (size_t)row * 64 + (q & 1) * 32);
    g0 = sp[0]; g1 = sp[1]; g2 = sp[2]; g3 = sp[3];
    int t2 = t0 + 2 * GRID_GEMM;
    sF = ei[t2 * TILE + e]; dF = ei[E_EDGES + t2 * TILE + e];
  }
  bar_lds();

  int pp = 0, sl = 0;
  for (int tile = t0; ; ) {
    const bool more = (tile + GRID_GEMM) < NTILES;

    if (more) {
      // stage t+1 from prefetched regs into the idle buffer
      uint4* dst = (uint4*)(&A[pp ^ 1][0] + e * KP + q * 32);
      dst[0] = g0; dst[1] = g1; dst[2] = g2; dst[3] = g3;
      if (w == 0) {
        ushort4 a0; a0.x = f2bf(av.x); a0.y = f2bf(av.y);
        a0.z = f2bf(av.z); a0.w = f2bf(av.w);
        *(ushort4*)(&A[pp ^ 1][0] + tid * KP + 128) = a0;
      }
      // gather t+2 (rows from in-flight ei), refill ei for t+3
      unsigned row = (q < 2) ? (unsigned)sF
                             : (((unsigned)sF & ~(unsigned)(NNODES - 1)) |
                                ((unsigned)dF & (unsigned)(NNODES - 1)));
      const uint4* sp = (const uint4*)(zb + (size_t)row * 64 + (q & 1) * 32);
      g0 = sp[0]; g1 = sp[1]; g2 = sp[2]; g3 = sp[3];
      int tn2 = tile + 2 * GRID_GEMM; if (tn2 > NTILES - 1) tn2 = NTILES - 1;
      if (w == 0) av = ((const float4*)attr)[tn2 * TILE + tid];
      int tn3 = tile + 3 * GRID_GEMM; if (tn3 > NTILES - 1) tn3 = NTILES - 1;
      sF = ei[tn3 * TILE + e]; dF = ei[E_EDGES + tn3 * TILE + e];
    }

    // ---- MFMA: 4 edge m-tiles sequentially, acc[2] reused (reg economy)
    const unsigned short* Ar = &A[pp][0];
#pragma unroll
    for (int mt = 0; mt < 4; ++mt) {
      const unsigned short* ap = Ar + (mt * 16 + l15) * KP;
      shortx8 afr[4], a4;
#pragma unroll
      for (int kk = 0; kk < 4; ++kk)
        afr[kk] = *(const shortx8*)(ap + kk * 32 + quad * 8);
      a4 = (quad == 0) ? *(const shortx8*)(ap + 128)
                       : (shortx8){0, 0, 0, 0, 0, 0, 0, 0};

      floatx4 acc[2];
      acc[0] = (floatx4){0.f, 0.f, 0.f, 0.f};
      acc[1] = (floatx4){0.f, 0.f, 0.f, 0.f};
#pragma unroll
      for (int kk = 0; kk < 4; ++kk)
#pragma unroll
        for (int nt = 0; nt < 2; ++nt)
          acc[nt] = __builtin_amdgcn_mfma_f32_16x16x32_bf16(
              afr[kk], bfr[nt][kk], acc[nt], 0, 0, 0);
#pragma unroll
      for (int nt = 0; nt < 2; ++nt)
        acc[nt] = __builtin_amdgcn_mfma_f32_16x16x32_bf16(
            a4, bfr4[nt], acc[nt], 0, 0, 0);

      // per-mt epilogue. C/D: col=l15 (channel), row=quad*4+r (edge in m-tile)
      if (!OUT) {
#pragma unroll
        for (int nt = 0; nt < 2; ++nt) {
          float s = 0.f, qq = 0.f;
#pragma unroll
          for (int r = 0; r < 4; ++r) {
            float h = acc[nt][r];
            s += h; qq += h * h;
          }
          ssum[nt] += s; ssq[nt] += qq;
        }
      } else {
#pragma unroll
        for (int r = 0; r < 4; ++r) {
          float t = 0.f;
#pragma unroll
          for (int nt = 0; nt < 2; ++nt) {
            float h = acc[nt][r];
            float p = fmaf(ea[nt], h, ebb[nt]);
            p = (p >= 0.f) ? p : 0.2f * p;
            t = fmaf(ew2[nt], p, t);
          }
          t += __shfl_xor(t, 1);
          t += __shfl_xor(t, 2);
          t += __shfl_xor(t, 4);
          t += __shfl_xor(t, 8);     // sum over this wave's 32 channels
          if (l15 == 0)
            po[sl][w][mt * 16 + quad * 4 + r] = t;
        }
      }
    }

    if (more || OUT) bar_lds();      // A[pp^1]+po visible; gathers stay in flight

    if (OUT && tid < TILE)
      out[tile * TILE + tid] = po[sl][0][tid] + po[sl][1][tid] +
                               po[sl][2][tid] + po[sl][3][tid] + b2v;

    if (!more) break;
    pp ^= 1; sl ^= 1;
    tile += GRID_GEMM;
  }

  if (!OUT) {   // flush: lanes of same l15 across quads hold disjoint edge sets
    float* gs = gstats + (blockIdx.x & (NSPREAD - 1)) * 2 * HCH;
#pragma unroll
    for (int nt = 0; nt < 2; ++nt) {
      float s = ssum[nt], qq = ssq[nt];
      s += __shfl_xor(s, 16); s += __shfl_xor(s, 32);
      qq += __shfl_xor(qq, 16); qq += __shfl_xor(qq, 32);
      if (quad == 0) {
        int c = w * 32 + nt * 16 + l15;
        atomicAdd(&gs[c], s);
        atomicAdd(&gs[HCH + c], qq);
      }
    }
  }
}

// -------------------------------------------------------------- launch ----
extern "C" void kernel_launch(void* const* d_in, const int* in_sizes, int n_in,
                              void* d_out, int out_size, void* d_ws, size_t ws_size,
                              hipStream_t stream) {
  const float* z     = (const float*)d_in[0];
  const float* attr  = (const float*)d_in[1];
  const float* W1    = (const float*)d_in[2];
  const float* b1    = (const float*)d_in[3];
  const float* gamma = (const float*)d_in[4];
  const float* beta  = (const float*)d_in[5];
  const float* W2    = (const float*)d_in[6];
  const float* b2    = (const float*)d_in[7];
  const int*   ei    = (const int*)d_in[8];
  float* out = (float*)d_out;

  char* ws = (char*)d_ws;
  unsigned short* zb  = (unsigned short*)ws;                 // 8,388,608 B
  unsigned short* w1t = (unsigned short*)(ws + 8388608);     //    34,816 B
  float* gstats       = (float*)(ws + 8423424);              //     8,192 B

  k_prep<<<ZBLK + WBLK + 1, 256, 0, stream>>>(z, W1, b1, zb, w1t, gstats);
  k_gemm<false><<<GRID_GEMM, 256, 0, stream>>>(zb, w1t, ei, attr, gstats,
                                               gamma, beta, W2, b2, nullptr);
  k_gemm<true><<<GRID_GEMM, 256, 0, stream>>>(zb, w1t, ei, attr, gstats,
                                              gamma, beta, W2, b2, out);
}